// Round 1
// baseline (631.854 us; speedup 1.0000x reference)
//
#include <hip/hip_runtime.h>
#include <hip/hip_bf16.h>
#include <math.h>

#define NROWS 100000
#define DIM 128
#define NGRAPH 16
#define NCHUNK 128
#define CHROWS 782   // ceil(100000/128)
#define EPSV 1e-12f

// workspace layout (float offsets)
#define SZ_SUMP (NGRAPH*NCHUNK*DIM)          // 262144
#define SZ_WV   (NGRAPH*2*DIM)               // 4096
#define SZ_OP   (NGRAPH*NCHUNK*2*DIM)        // 524288
#define OFF_SUMP 0
#define OFF_WV1 (OFF_SUMP + SZ_SUMP)
#define OFF_C1  (OFF_WV1 + SZ_WV)
#define OFF_O1P (OFF_C1 + 32)
#define OFF_WV2 (OFF_O1P + SZ_OP)
#define OFF_C2  (OFF_WV2 + SZ_WV)
#define OFF_O2P (OFF_C2 + 32)
#define OFF_G   (OFF_O2P + SZ_OP)            // [16][256]
#define OFF_S   (OFF_G + NGRAPH*256)         // [8][16]

__device__ __forceinline__ const float* graph_ptr(const float* x1, const float* x2, int g) {
    return (g < 8) ? (x1 + (size_t)g * NROWS * DIM) : (x2 + (size_t)(g - 8) * NROWS * DIM);
}

// Pass 1: per-chunk column sums of each graph -> sump[g][c][128]
__global__ __launch_bounds__(256) void k_sum(const float* __restrict__ x1,
                                             const float* __restrict__ x2,
                                             float* __restrict__ sump) {
    int g = blockIdx.x >> 7, c = blockIdx.x & (NCHUNK - 1);
    const float* xg = graph_ptr(x1, x2, g);
    int lane = threadIdx.x & 31, grp = threadIdx.x >> 5;
    int col = lane * 4;
    float ax = 0.f, ay = 0.f, az = 0.f, aw = 0.f;
    int r0 = c * CHROWS, r1 = min(r0 + CHROWS, NROWS);
    for (int r = r0 + grp; r < r1; r += 8) {
        float4 v = *reinterpret_cast<const float4*>(xg + (size_t)r * DIM + col);
        ax += v.x; ay += v.y; az += v.z; aw += v.w;
    }
    __shared__ float4 lds[256];
    lds[threadIdx.x] = make_float4(ax, ay, az, aw);
    __syncthreads();
    if (threadIdx.x < 32) {
        float4 t = lds[threadIdx.x];
        for (int k = 1; k < 8; ++k) {
            float4 o = lds[k * 32 + threadIdx.x];
            t.x += o.x; t.y += o.y; t.z += o.z; t.w += o.w;
        }
        *reinterpret_cast<float4*>(sump + ((size_t)g * NCHUNK + c) * DIM + threadIdx.x * 4) = t;
    }
}

// Glue: mean -> h = tanh(mean@W) -> wvec = Va + Wt@h, c = Vb.h + b
__global__ __launch_bounds__(128) void k_prep(const float* __restrict__ src, int phase,
                                              const float* __restrict__ W_att,
                                              const float* __restrict__ V_att,
                                              const float* __restrict__ Wt_att,
                                              const float* __restrict__ b_att,
                                              float* __restrict__ wv, float* __restrict__ cc) {
    int g = blockIdx.x >> 1, i = blockIdx.x & 1;
    int t = threadIdx.x;
    __shared__ float mean[DIM], h[DIM], red[DIM];
    float s = 0.f;
    if (phase == 1) {
        for (int c = 0; c < NCHUNK; ++c) s += src[((size_t)g * NCHUNK + c) * DIM + t];
    } else {
        for (int c = 0; c < NCHUNK; ++c) s += src[(((size_t)g * NCHUNK + c) * 2 + i) * DIM + t];
    }
    mean[t] = s / (float)NROWS;
    __syncthreads();
    const float* W = W_att + (size_t)i * DIM * DIM;
    float hv = 0.f;
    for (int d = 0; d < DIM; ++d) hv = fmaf(mean[d], W[d * DIM + t], hv);
    h[t] = tanhf(hv);
    __syncthreads();
    const float* Va = V_att + (size_t)i * 2 * DIM;
    const float* Vb = Va + DIM;
    const float* Wt = Wt_att + (size_t)i * DIM * DIM;
    float w = Va[t];
    for (int e = 0; e < DIM; ++e) w = fmaf(Wt[t * DIM + e], h[e], w);
    wv[((size_t)g * 2 + i) * DIM + t] = w;
    red[t] = Vb[t] * h[t];
    __syncthreads();
    for (int k = 64; k; k >>= 1) { if (t < k) red[t] += red[t + k]; __syncthreads(); }
    if (t == 0) cc[g * 2 + i] = red[0] + b_att[i];
}

__device__ __forceinline__ float wave32_sum(float v) {
    #pragma unroll
    for (int m = 16; m; m >>= 1) v += __shfl_xor(v, m, 64);
    return v;
}

__device__ __forceinline__ float att_of(float s, float u) {
    float t = s / fmaxf(fabsf(s), EPSV);
    return u * (1.f / (1.f + expf(-t)));
}

// Pass 2: att1 per row, accumulate out1 = sum att1*x  (per-chunk partials)
__global__ __launch_bounds__(256) void k_pass2(const float* __restrict__ x1,
                                               const float* __restrict__ x2,
                                               const float* __restrict__ wv1,
                                               const float* __restrict__ c1,
                                               const float* __restrict__ U_att,
                                               float* __restrict__ o1p) {
    int g = blockIdx.x >> 7, c = blockIdx.x & (NCHUNK - 1);
    const float* xg = graph_ptr(x1, x2, g);
    int lane = threadIdx.x & 31, grp = threadIdx.x >> 5;
    int col = lane * 4;
    float4 w0 = *reinterpret_cast<const float4*>(wv1 + ((size_t)g * 2 + 0) * DIM + col);
    float4 w1 = *reinterpret_cast<const float4*>(wv1 + ((size_t)g * 2 + 1) * DIM + col);
    float cc0 = c1[g * 2 + 0], cc1 = c1[g * 2 + 1];
    float u0 = U_att[0], u1 = U_att[1];
    float4 a0 = make_float4(0, 0, 0, 0), a1 = make_float4(0, 0, 0, 0);
    int r0 = c * CHROWS, r1 = min(r0 + CHROWS, NROWS);
    for (int r = r0 + grp; r < r1; r += 8) {
        float4 v = *reinterpret_cast<const float4*>(xg + (size_t)r * DIM + col);
        float d0 = v.x * w0.x; d0 = fmaf(v.y, w0.y, d0); d0 = fmaf(v.z, w0.z, d0); d0 = fmaf(v.w, w0.w, d0);
        float d1 = v.x * w1.x; d1 = fmaf(v.y, w1.y, d1); d1 = fmaf(v.z, w1.z, d1); d1 = fmaf(v.w, w1.w, d1);
        d0 = wave32_sum(d0); d1 = wave32_sum(d1);
        float at0 = att_of(d0 + cc0, u0);
        float at1 = att_of(d1 + cc1, u1);
        a0.x = fmaf(at0, v.x, a0.x); a0.y = fmaf(at0, v.y, a0.y); a0.z = fmaf(at0, v.z, a0.z); a0.w = fmaf(at0, v.w, a0.w);
        a1.x = fmaf(at1, v.x, a1.x); a1.y = fmaf(at1, v.y, a1.y); a1.z = fmaf(at1, v.z, a1.z); a1.w = fmaf(at1, v.w, a1.w);
    }
    __shared__ float4 lds0[256];
    __shared__ float4 lds1[256];
    lds0[threadIdx.x] = a0; lds1[threadIdx.x] = a1;
    __syncthreads();
    int t = threadIdx.x;
    if (t < 64) {
        int i = t >> 5, l = t & 31;
        const float4* src = i ? lds1 : lds0;
        float4 tt = src[l];
        for (int k = 1; k < 8; ++k) {
            float4 o = src[k * 32 + l];
            tt.x += o.x; tt.y += o.y; tt.z += o.z; tt.w += o.w;
        }
        *reinterpret_cast<float4*>(o1p + (((size_t)g * NCHUNK + c) * 2 + i) * DIM + l * 4) = tt;
    }
}

// Pass 3: recompute att1, compute att2 (s2 = att1*dot(x,wvec2)+c2), accumulate att1*att2*x
__global__ __launch_bounds__(256) void k_pass3(const float* __restrict__ x1,
                                               const float* __restrict__ x2,
                                               const float* __restrict__ wv1,
                                               const float* __restrict__ c1,
                                               const float* __restrict__ wv2,
                                               const float* __restrict__ c2,
                                               const float* __restrict__ U_att,
                                               float* __restrict__ o2p) {
    int g = blockIdx.x >> 7, c = blockIdx.x & (NCHUNK - 1);
    const float* xg = graph_ptr(x1, x2, g);
    int lane = threadIdx.x & 31, grp = threadIdx.x >> 5;
    int col = lane * 4;
    float4 w0a = *reinterpret_cast<const float4*>(wv1 + ((size_t)g * 2 + 0) * DIM + col);
    float4 w1a = *reinterpret_cast<const float4*>(wv1 + ((size_t)g * 2 + 1) * DIM + col);
    float4 w0b = *reinterpret_cast<const float4*>(wv2 + ((size_t)g * 2 + 0) * DIM + col);
    float4 w1b = *reinterpret_cast<const float4*>(wv2 + ((size_t)g * 2 + 1) * DIM + col);
    float cA0 = c1[g * 2 + 0], cA1 = c1[g * 2 + 1];
    float cB0 = c2[g * 2 + 0], cB1 = c2[g * 2 + 1];
    float u0 = U_att[0], u1 = U_att[1];
    float4 a0 = make_float4(0, 0, 0, 0), a1 = make_float4(0, 0, 0, 0);
    int r0 = c * CHROWS, r1 = min(r0 + CHROWS, NROWS);
    for (int r = r0 + grp; r < r1; r += 8) {
        float4 v = *reinterpret_cast<const float4*>(xg + (size_t)r * DIM + col);
        float d0a = v.x * w0a.x; d0a = fmaf(v.y, w0a.y, d0a); d0a = fmaf(v.z, w0a.z, d0a); d0a = fmaf(v.w, w0a.w, d0a);
        float d1a = v.x * w1a.x; d1a = fmaf(v.y, w1a.y, d1a); d1a = fmaf(v.z, w1a.z, d1a); d1a = fmaf(v.w, w1a.w, d1a);
        float d0b = v.x * w0b.x; d0b = fmaf(v.y, w0b.y, d0b); d0b = fmaf(v.z, w0b.z, d0b); d0b = fmaf(v.w, w0b.w, d0b);
        float d1b = v.x * w1b.x; d1b = fmaf(v.y, w1b.y, d1b); d1b = fmaf(v.z, w1b.z, d1b); d1b = fmaf(v.w, w1b.w, d1b);
        d0a = wave32_sum(d0a); d1a = wave32_sum(d1a);
        d0b = wave32_sum(d0b); d1b = wave32_sum(d1b);
        float at10 = att_of(d0a + cA0, u0);
        float at11 = att_of(d1a + cA1, u1);
        float at20 = att_of(fmaf(at10, d0b, cB0), u0);
        float at21 = att_of(fmaf(at11, d1b, cB1), u1);
        float f0 = at10 * at20, f1 = at11 * at21;
        a0.x = fmaf(f0, v.x, a0.x); a0.y = fmaf(f0, v.y, a0.y); a0.z = fmaf(f0, v.z, a0.z); a0.w = fmaf(f0, v.w, a0.w);
        a1.x = fmaf(f1, v.x, a1.x); a1.y = fmaf(f1, v.y, a1.y); a1.z = fmaf(f1, v.z, a1.z); a1.w = fmaf(f1, v.w, a1.w);
    }
    __shared__ float4 lds0[256];
    __shared__ float4 lds1[256];
    lds0[threadIdx.x] = a0; lds1[threadIdx.x] = a1;
    __syncthreads();
    int t = threadIdx.x;
    if (t < 64) {
        int i = t >> 5, l = t & 31;
        const float4* src = i ? lds1 : lds0;
        float4 tt = src[l];
        for (int k = 1; k < 8; ++k) {
            float4 o = src[k * 32 + l];
            tt.x += o.x; tt.y += o.y; tt.z += o.z; tt.w += o.w;
        }
        *reinterpret_cast<float4*>(o2p + (((size_t)g * NCHUNK + c) * 2 + i) * DIM + l * 4) = tt;
    }
}

// Reduce per-chunk out2 partials -> g vectors [16][256] (concat i=0, i=1)
__global__ __launch_bounds__(256) void k_reduceG(const float* __restrict__ o2p,
                                                 float* __restrict__ gv) {
    int g = blockIdx.x, t = threadIdx.x;
    int i = t >> 7, d = t & 127;
    float s = 0.f;
    for (int c = 0; c < NCHUNK; ++c) s += o2p[(((size_t)g * NCHUNK + c) * 2 + i) * DIM + d];
    gv[(size_t)g * 256 + t] = s;
}

// NTN raw scores: one block per (pair b, feature f)
__global__ __launch_bounds__(256) void k_ntn(const float* __restrict__ gv,
                                             const float* __restrict__ V_ntn,
                                             const float* __restrict__ W_ntn,
                                             const float* __restrict__ b_ntn,
                                             float* __restrict__ sout) {
    int b = blockIdx.x >> 4, f = blockIdx.x & 15;
    int e = threadIdx.x;
    __shared__ float g1s[256], g2s[256], red[256];
    g1s[e] = gv[(size_t)b * 256 + e];
    g2s[e] = gv[(size_t)(8 + b) * 256 + e];
    __syncthreads();
    const float* Wf = W_ntn + (size_t)f * 256 * 256;
    float acc = 0.f;
    for (int d = 0; d < 256; ++d) acc = fmaf(Wf[(size_t)d * 256 + e], g1s[d], acc);
    float p = acc * g2s[e];
    p = fmaf(V_ntn[(size_t)f * 512 + e], g1s[e], p);
    p = fmaf(V_ntn[(size_t)f * 512 + 256 + e], g2s[e], p);
    red[e] = p;
    __syncthreads();
    for (int k = 128; k; k >>= 1) { if (e < k) red[e] += red[e + k]; __syncthreads(); }
    if (e == 0) sout[b * 16 + f] = red[0] + b_ntn[f];
}

// Final: l1-normalize, relu, projection chain -> out[b]
__global__ __launch_bounds__(64) void k_out(const float* __restrict__ sout,
                                            const float* __restrict__ p0,
                                            const float* __restrict__ p1,
                                            const float* __restrict__ p2,
                                            const float* __restrict__ p3,
                                            float* __restrict__ out) {
    int b = blockIdx.x;
    if (threadIdx.x != 0) return;
    float s[16]; float l1 = 0.f;
    for (int f = 0; f < 16; ++f) { s[f] = sout[b * 16 + f]; l1 += fabsf(s[f]); }
    float inv = 1.f / fmaxf(l1, EPSV);
    float y[16];
    for (int f = 0; f < 16; ++f) { float t = s[f] * inv; y[f] = t > 0.f ? t : 0.f; }
    float v2[4], v1[8], P[16];
    for (int j = 0; j < 4; ++j) v2[j] = p3[0] * p2[j] + p3[1] * p2[4 + j];
    for (int j = 0; j < 8; ++j) { float a = 0.f; for (int k = 0; k < 4; ++k) a = fmaf(v2[k], p1[k * 8 + j], a); v1[j] = a; }
    for (int j = 0; j < 16; ++j) { float a = 0.f; for (int k = 0; k < 8; ++k) a = fmaf(v1[k], p0[k * 16 + j], a); P[j] = a; }
    float o = 0.f;
    for (int f = 0; f < 16; ++f) o = fmaf(P[f], y[f], o);
    out[b] = o;
}

extern "C" void kernel_launch(void* const* d_in, const int* in_sizes, int n_in,
                              void* d_out, int out_size, void* d_ws, size_t ws_size,
                              hipStream_t stream) {
    const float* x1    = (const float*)d_in[0];
    const float* x2    = (const float*)d_in[1];
    const float* W_att = (const float*)d_in[2];
    const float* V_att = (const float*)d_in[3];
    const float* Wt_att= (const float*)d_in[4];
    const float* U_att = (const float*)d_in[5];
    const float* b_att = (const float*)d_in[6];
    const float* V_ntn = (const float*)d_in[7];
    const float* W_ntn = (const float*)d_in[8];
    const float* b_ntn = (const float*)d_in[9];
    const float* p0    = (const float*)d_in[10];
    const float* p1    = (const float*)d_in[11];
    const float* p2    = (const float*)d_in[12];
    const float* p3    = (const float*)d_in[13];
    float* ws  = (float*)d_ws;
    float* out = (float*)d_out;

    k_sum<<<NGRAPH * NCHUNK, 256, 0, stream>>>(x1, x2, ws + OFF_SUMP);
    k_prep<<<NGRAPH * 2, 128, 0, stream>>>(ws + OFF_SUMP, 1, W_att, V_att, Wt_att, b_att,
                                           ws + OFF_WV1, ws + OFF_C1);
    k_pass2<<<NGRAPH * NCHUNK, 256, 0, stream>>>(x1, x2, ws + OFF_WV1, ws + OFF_C1, U_att,
                                                 ws + OFF_O1P);
    k_prep<<<NGRAPH * 2, 128, 0, stream>>>(ws + OFF_O1P, 2, W_att, V_att, Wt_att, b_att,
                                           ws + OFF_WV2, ws + OFF_C2);
    k_pass3<<<NGRAPH * NCHUNK, 256, 0, stream>>>(x1, x2, ws + OFF_WV1, ws + OFF_C1,
                                                 ws + OFF_WV2, ws + OFF_C2, U_att,
                                                 ws + OFF_O2P);
    k_reduceG<<<NGRAPH, 256, 0, stream>>>(ws + OFF_O2P, ws + OFF_G);
    k_ntn<<<8 * 16, 256, 0, stream>>>(ws + OFF_G, V_ntn, W_ntn, b_ntn, ws + OFF_S);
    k_out<<<8, 64, 0, stream>>>(ws + OFF_S, p0, p1, p2, p3, out);
}

// Round 2
// 533.656 us; speedup vs baseline: 1.1840x; 1.1840x over previous
//
#include <hip/hip_runtime.h>
#include <hip/hip_bf16.h>
#include <math.h>

#define NROWS 100000
#define DIM 128
#define NGRAPH 16
#define NCHUNK 128
#define CHROWS 782   // ceil(100000/128)
#define EPSV 1e-12f

// workspace layout (float offsets)
#define SZ_SUMP (NGRAPH*NCHUNK*DIM)          // 262144
#define SZ_WV   (NGRAPH*2*DIM)               // 4096
#define SZ_OP   (NGRAPH*NCHUNK*2*DIM)        // 524288
#define OFF_SUMP 0
#define OFF_WV1 (OFF_SUMP + SZ_SUMP)
#define OFF_C1  (OFF_WV1 + SZ_WV)
#define OFF_O1P (OFF_C1 + 32)
#define OFF_WV2 (OFF_O1P + SZ_OP)
#define OFF_C2  (OFF_WV2 + SZ_WV)
#define OFF_O2P (OFF_C2 + 32)
#define OFF_G   (OFF_O2P + SZ_OP)            // [16][256]
#define OFF_S   (OFF_G + NGRAPH*256)         // [8][16]

__device__ __forceinline__ const float* graph_ptr(const float* x1, const float* x2, int g) {
    return (g < 8) ? (x1 + (size_t)g * NROWS * DIM) : (x2 + (size_t)(g - 8) * NROWS * DIM);
}

// Pass 1: per-chunk column sums of each graph -> sump[g][c][128]
__global__ __launch_bounds__(256) void k_sum(const float* __restrict__ x1,
                                             const float* __restrict__ x2,
                                             float* __restrict__ sump) {
    int g = blockIdx.x >> 7, c = blockIdx.x & (NCHUNK - 1);
    const float* xg = graph_ptr(x1, x2, g);
    int lane = threadIdx.x & 31, grp = threadIdx.x >> 5;
    int col = lane * 4;
    float ax = 0.f, ay = 0.f, az = 0.f, aw = 0.f;
    int r0 = c * CHROWS, r1 = min(r0 + CHROWS, NROWS);
    for (int r = r0 + grp; r < r1; r += 8) {
        float4 v = *reinterpret_cast<const float4*>(xg + (size_t)r * DIM + col);
        ax += v.x; ay += v.y; az += v.z; aw += v.w;
    }
    __shared__ float4 lds[256];
    lds[threadIdx.x] = make_float4(ax, ay, az, aw);
    __syncthreads();
    if (threadIdx.x < 32) {
        float4 t = lds[threadIdx.x];
        for (int k = 1; k < 8; ++k) {
            float4 o = lds[k * 32 + threadIdx.x];
            t.x += o.x; t.y += o.y; t.z += o.z; t.w += o.w;
        }
        *reinterpret_cast<float4*>(sump + ((size_t)g * NCHUNK + c) * DIM + threadIdx.x * 4) = t;
    }
}

// Glue: mean -> h = tanh(mean@W) -> wvec = Va + Wt@h, c = Vb.h + b
__global__ __launch_bounds__(128) void k_prep(const float* __restrict__ src, int phase,
                                              const float* __restrict__ W_att,
                                              const float* __restrict__ V_att,
                                              const float* __restrict__ Wt_att,
                                              const float* __restrict__ b_att,
                                              float* __restrict__ wv, float* __restrict__ cc) {
    int g = blockIdx.x >> 1, i = blockIdx.x & 1;
    int t = threadIdx.x;
    __shared__ float mean[DIM], h[DIM], red[DIM];
    float s = 0.f;
    if (phase == 1) {
        for (int c = 0; c < NCHUNK; ++c) s += src[((size_t)g * NCHUNK + c) * DIM + t];
    } else {
        for (int c = 0; c < NCHUNK; ++c) s += src[(((size_t)g * NCHUNK + c) * 2 + i) * DIM + t];
    }
    mean[t] = s / (float)NROWS;
    __syncthreads();
    const float* W = W_att + (size_t)i * DIM * DIM;
    float hv = 0.f;
    for (int d = 0; d < DIM; ++d) hv = fmaf(mean[d], W[d * DIM + t], hv);
    h[t] = tanhf(hv);
    __syncthreads();
    const float* Va = V_att + (size_t)i * 2 * DIM;
    const float* Vb = Va + DIM;
    const float* Wt = Wt_att + (size_t)i * DIM * DIM;
    float w = Va[t];
    for (int e = 0; e < DIM; ++e) w = fmaf(Wt[t * DIM + e], h[e], w);
    wv[((size_t)g * 2 + i) * DIM + t] = w;
    red[t] = Vb[t] * h[t];
    __syncthreads();
    for (int k = 64; k; k >>= 1) { if (t < k) red[t] += red[t + k]; __syncthreads(); }
    if (t == 0) cc[g * 2 + i] = red[0] + b_att[i];
}

__device__ __forceinline__ float wave32_sum(float v) {
    #pragma unroll
    for (int m = 16; m; m >>= 1) v += __shfl_xor(v, m, 64);
    return v;
}

// att = u * sigmoid(s / max(|s|, eps))
// s/max(|s|,eps) == clamp(s*1e12, -1, 1) exactly:
//   |s| >= eps -> sign(s) = +-1 ; |s| < eps -> s/eps = s*1e12 (clamp is no-op)
// sigmoid via v_exp_f32 + v_rcp_f32 (err ~1e-7, threshold is 3.2e-4)
__device__ __forceinline__ float att_of(float s, float u) {
    float t = fminf(fmaxf(s * 1e12f, -1.f), 1.f);
    float e = __expf(-t);
    return u * __builtin_amdgcn_rcpf(1.f + e);
}

// Pass 2: att1 per row, accumulate out1 = sum att1*x  (per-chunk partials)
__global__ __launch_bounds__(256) void k_pass2(const float* __restrict__ x1,
                                               const float* __restrict__ x2,
                                               const float* __restrict__ wv1,
                                               const float* __restrict__ c1,
                                               const float* __restrict__ U_att,
                                               float* __restrict__ o1p) {
    int g = blockIdx.x >> 7, c = blockIdx.x & (NCHUNK - 1);
    const float* xg = graph_ptr(x1, x2, g);
    int lane = threadIdx.x & 31, grp = threadIdx.x >> 5;
    int col = lane * 4;
    float4 w0 = *reinterpret_cast<const float4*>(wv1 + ((size_t)g * 2 + 0) * DIM + col);
    float4 w1 = *reinterpret_cast<const float4*>(wv1 + ((size_t)g * 2 + 1) * DIM + col);
    float cc0 = c1[g * 2 + 0], cc1 = c1[g * 2 + 1];
    float u0 = U_att[0], u1 = U_att[1];
    float4 a0 = make_float4(0, 0, 0, 0), a1 = make_float4(0, 0, 0, 0);
    int r0 = c * CHROWS, r1 = min(r0 + CHROWS, NROWS);
    for (int r = r0 + grp; r < r1; r += 8) {
        float4 v = *reinterpret_cast<const float4*>(xg + (size_t)r * DIM + col);
        float d0 = v.x * w0.x; d0 = fmaf(v.y, w0.y, d0); d0 = fmaf(v.z, w0.z, d0); d0 = fmaf(v.w, w0.w, d0);
        float d1 = v.x * w1.x; d1 = fmaf(v.y, w1.y, d1); d1 = fmaf(v.z, w1.z, d1); d1 = fmaf(v.w, w1.w, d1);
        d0 = wave32_sum(d0); d1 = wave32_sum(d1);
        float at0 = att_of(d0 + cc0, u0);
        float at1 = att_of(d1 + cc1, u1);
        a0.x = fmaf(at0, v.x, a0.x); a0.y = fmaf(at0, v.y, a0.y); a0.z = fmaf(at0, v.z, a0.z); a0.w = fmaf(at0, v.w, a0.w);
        a1.x = fmaf(at1, v.x, a1.x); a1.y = fmaf(at1, v.y, a1.y); a1.z = fmaf(at1, v.z, a1.z); a1.w = fmaf(at1, v.w, a1.w);
    }
    __shared__ float4 lds0[256];
    __shared__ float4 lds1[256];
    lds0[threadIdx.x] = a0; lds1[threadIdx.x] = a1;
    __syncthreads();
    int t = threadIdx.x;
    if (t < 64) {
        int i = t >> 5, l = t & 31;
        const float4* src = i ? lds1 : lds0;
        float4 tt = src[l];
        for (int k = 1; k < 8; ++k) {
            float4 o = src[k * 32 + l];
            tt.x += o.x; tt.y += o.y; tt.z += o.z; tt.w += o.w;
        }
        *reinterpret_cast<float4*>(o1p + (((size_t)g * NCHUNK + c) * 2 + i) * DIM + l * 4) = tt;
    }
}

// Pass 3: recompute att1, compute att2 (s2 = att1*dot(x,wvec2)+c2), accumulate att1*att2*x
__global__ __launch_bounds__(256) void k_pass3(const float* __restrict__ x1,
                                               const float* __restrict__ x2,
                                               const float* __restrict__ wv1,
                                               const float* __restrict__ c1,
                                               const float* __restrict__ wv2,
                                               const float* __restrict__ c2,
                                               const float* __restrict__ U_att,
                                               float* __restrict__ o2p) {
    int g = blockIdx.x >> 7, c = blockIdx.x & (NCHUNK - 1);
    const float* xg = graph_ptr(x1, x2, g);
    int lane = threadIdx.x & 31, grp = threadIdx.x >> 5;
    int col = lane * 4;
    float4 w0a = *reinterpret_cast<const float4*>(wv1 + ((size_t)g * 2 + 0) * DIM + col);
    float4 w1a = *reinterpret_cast<const float4*>(wv1 + ((size_t)g * 2 + 1) * DIM + col);
    float4 w0b = *reinterpret_cast<const float4*>(wv2 + ((size_t)g * 2 + 0) * DIM + col);
    float4 w1b = *reinterpret_cast<const float4*>(wv2 + ((size_t)g * 2 + 1) * DIM + col);
    float cA0 = c1[g * 2 + 0], cA1 = c1[g * 2 + 1];
    float cB0 = c2[g * 2 + 0], cB1 = c2[g * 2 + 1];
    float u0 = U_att[0], u1 = U_att[1];
    float4 a0 = make_float4(0, 0, 0, 0), a1 = make_float4(0, 0, 0, 0);
    int r0 = c * CHROWS, r1 = min(r0 + CHROWS, NROWS);
    for (int r = r0 + grp; r < r1; r += 8) {
        float4 v = *reinterpret_cast<const float4*>(xg + (size_t)r * DIM + col);
        float d0a = v.x * w0a.x; d0a = fmaf(v.y, w0a.y, d0a); d0a = fmaf(v.z, w0a.z, d0a); d0a = fmaf(v.w, w0a.w, d0a);
        float d1a = v.x * w1a.x; d1a = fmaf(v.y, w1a.y, d1a); d1a = fmaf(v.z, w1a.z, d1a); d1a = fmaf(v.w, w1a.w, d1a);
        float d0b = v.x * w0b.x; d0b = fmaf(v.y, w0b.y, d0b); d0b = fmaf(v.z, w0b.z, d0b); d0b = fmaf(v.w, w0b.w, d0b);
        float d1b = v.x * w1b.x; d1b = fmaf(v.y, w1b.y, d1b); d1b = fmaf(v.z, w1b.z, d1b); d1b = fmaf(v.w, w1b.w, d1b);
        d0a = wave32_sum(d0a); d1a = wave32_sum(d1a);
        d0b = wave32_sum(d0b); d1b = wave32_sum(d1b);
        float at10 = att_of(d0a + cA0, u0);
        float at11 = att_of(d1a + cA1, u1);
        float at20 = att_of(fmaf(at10, d0b, cB0), u0);
        float at21 = att_of(fmaf(at11, d1b, cB1), u1);
        float f0 = at10 * at20, f1 = at11 * at21;
        a0.x = fmaf(f0, v.x, a0.x); a0.y = fmaf(f0, v.y, a0.y); a0.z = fmaf(f0, v.z, a0.z); a0.w = fmaf(f0, v.w, a0.w);
        a1.x = fmaf(f1, v.x, a1.x); a1.y = fmaf(f1, v.y, a1.y); a1.z = fmaf(f1, v.z, a1.z); a1.w = fmaf(f1, v.w, a1.w);
    }
    __shared__ float4 lds0[256];
    __shared__ float4 lds1[256];
    lds0[threadIdx.x] = a0; lds1[threadIdx.x] = a1;
    __syncthreads();
    int t = threadIdx.x;
    if (t < 64) {
        int i = t >> 5, l = t & 31;
        const float4* src = i ? lds1 : lds0;
        float4 tt = src[l];
        for (int k = 1; k < 8; ++k) {
            float4 o = src[k * 32 + l];
            tt.x += o.x; tt.y += o.y; tt.z += o.z; tt.w += o.w;
        }
        *reinterpret_cast<float4*>(o2p + (((size_t)g * NCHUNK + c) * 2 + i) * DIM + l * 4) = tt;
    }
}

// Reduce per-chunk out2 partials -> g vectors [16][256] (concat i=0, i=1)
__global__ __launch_bounds__(256) void k_reduceG(const float* __restrict__ o2p,
                                                 float* __restrict__ gv) {
    int g = blockIdx.x, t = threadIdx.x;
    int i = t >> 7, d = t & 127;
    float s = 0.f;
    for (int c = 0; c < NCHUNK; ++c) s += o2p[(((size_t)g * NCHUNK + c) * 2 + i) * DIM + d];
    gv[(size_t)g * 256 + t] = s;
}

// NTN raw scores: one block per (pair b, feature f)
__global__ __launch_bounds__(256) void k_ntn(const float* __restrict__ gv,
                                             const float* __restrict__ V_ntn,
                                             const float* __restrict__ W_ntn,
                                             const float* __restrict__ b_ntn,
                                             float* __restrict__ sout) {
    int b = blockIdx.x >> 4, f = blockIdx.x & 15;
    int e = threadIdx.x;
    __shared__ float g1s[256], g2s[256], red[256];
    g1s[e] = gv[(size_t)b * 256 + e];
    g2s[e] = gv[(size_t)(8 + b) * 256 + e];
    __syncthreads();
    const float* Wf = W_ntn + (size_t)f * 256 * 256;
    float acc = 0.f;
    for (int d = 0; d < 256; ++d) acc = fmaf(Wf[(size_t)d * 256 + e], g1s[d], acc);
    float p = acc * g2s[e];
    p = fmaf(V_ntn[(size_t)f * 512 + e], g1s[e], p);
    p = fmaf(V_ntn[(size_t)f * 512 + 256 + e], g2s[e], p);
    red[e] = p;
    __syncthreads();
    for (int k = 128; k; k >>= 1) { if (e < k) red[e] += red[e + k]; __syncthreads(); }
    if (e == 0) sout[b * 16 + f] = red[0] + b_ntn[f];
}

// Final: l1-normalize, relu, projection chain -> out[b]
__global__ __launch_bounds__(64) void k_out(const float* __restrict__ sout,
                                            const float* __restrict__ p0,
                                            const float* __restrict__ p1,
                                            const float* __restrict__ p2,
                                            const float* __restrict__ p3,
                                            float* __restrict__ out) {
    int b = blockIdx.x;
    if (threadIdx.x != 0) return;
    float s[16]; float l1 = 0.f;
    for (int f = 0; f < 16; ++f) { s[f] = sout[b * 16 + f]; l1 += fabsf(s[f]); }
    float inv = 1.f / fmaxf(l1, EPSV);
    float y[16];
    for (int f = 0; f < 16; ++f) { float t = s[f] * inv; y[f] = t > 0.f ? t : 0.f; }
    float v2[4], v1[8], P[16];
    for (int j = 0; j < 4; ++j) v2[j] = p3[0] * p2[j] + p3[1] * p2[4 + j];
    for (int j = 0; j < 8; ++j) { float a = 0.f; for (int k = 0; k < 4; ++k) a = fmaf(v2[k], p1[k * 8 + j], a); v1[j] = a; }
    for (int j = 0; j < 16; ++j) { float a = 0.f; for (int k = 0; k < 8; ++k) a = fmaf(v1[k], p0[k * 16 + j], a); P[j] = a; }
    float o = 0.f;
    for (int f = 0; f < 16; ++f) o = fmaf(P[f], y[f], o);
    out[b] = o;
}

extern "C" void kernel_launch(void* const* d_in, const int* in_sizes, int n_in,
                              void* d_out, int out_size, void* d_ws, size_t ws_size,
                              hipStream_t stream) {
    const float* x1    = (const float*)d_in[0];
    const float* x2    = (const float*)d_in[1];
    const float* W_att = (const float*)d_in[2];
    const float* V_att = (const float*)d_in[3];
    const float* Wt_att= (const float*)d_in[4];
    const float* U_att = (const float*)d_in[5];
    const float* b_att = (const float*)d_in[6];
    const float* V_ntn = (const float*)d_in[7];
    const float* W_ntn = (const float*)d_in[8];
    const float* b_ntn = (const float*)d_in[9];
    const float* p0    = (const float*)d_in[10];
    const float* p1    = (const float*)d_in[11];
    const float* p2    = (const float*)d_in[12];
    const float* p3    = (const float*)d_in[13];
    float* ws  = (float*)d_ws;
    float* out = (float*)d_out;

    k_sum<<<NGRAPH * NCHUNK, 256, 0, stream>>>(x1, x2, ws + OFF_SUMP);
    k_prep<<<NGRAPH * 2, 128, 0, stream>>>(ws + OFF_SUMP, 1, W_att, V_att, Wt_att, b_att,
                                           ws + OFF_WV1, ws + OFF_C1);
    k_pass2<<<NGRAPH * NCHUNK, 256, 0, stream>>>(x1, x2, ws + OFF_WV1, ws + OFF_C1, U_att,
                                                 ws + OFF_O1P);
    k_prep<<<NGRAPH * 2, 128, 0, stream>>>(ws + OFF_O1P, 2, W_att, V_att, Wt_att, b_att,
                                           ws + OFF_WV2, ws + OFF_C2);
    k_pass3<<<NGRAPH * NCHUNK, 256, 0, stream>>>(x1, x2, ws + OFF_WV1, ws + OFF_C1,
                                                 ws + OFF_WV2, ws + OFF_C2, U_att,
                                                 ws + OFF_O2P);
    k_reduceG<<<NGRAPH, 256, 0, stream>>>(ws + OFF_O2P, ws + OFF_G);
    k_ntn<<<8 * 16, 256, 0, stream>>>(ws + OFF_G, V_ntn, W_ntn, b_ntn, ws + OFF_S);
    k_out<<<8, 64, 0, stream>>>(ws + OFF_S, p0, p1, p2, p3, out);
}

// Round 3
// 476.216 us; speedup vs baseline: 1.3268x; 1.1206x over previous
//
#include <hip/hip_runtime.h>
#include <hip/hip_bf16.h>
#include <math.h>

#define NROWS 100000
#define DIM 128
#define NGRAPH 16
#define NCHUNK 128
#define CHROWS 782   // ceil(100000/128)
#define EPSV 1e-12f

// workspace layout (float offsets)
#define SZ_SUMP (NGRAPH*NCHUNK*DIM)          // 262144
#define SZ_WV   (NGRAPH*2*DIM)               // 4096
#define SZ_OP   (NGRAPH*NCHUNK*2*DIM)        // 524288
#define OFF_SUMP 0
#define OFF_WV1 (OFF_SUMP + SZ_SUMP)
#define OFF_C1  (OFF_WV1 + SZ_WV)
#define OFF_O1P (OFF_C1 + 32)
#define OFF_WV2 (OFF_O1P + SZ_OP)
#define OFF_C2  (OFF_WV2 + SZ_WV)
#define OFF_O2P (OFF_C2 + 32)
#define OFF_G   (OFF_O2P + SZ_OP)            // [16][256]
#define OFF_S   (OFF_G + NGRAPH*256)         // [8][16]

__device__ __forceinline__ const float* graph_ptr(const float* x1, const float* x2, int g) {
    return (g < 8) ? (x1 + (size_t)g * NROWS * DIM) : (x2 + (size_t)(g - 8) * NROWS * DIM);
}

// 16-lane all-reduce sum entirely on the VALU pipe via DPP (no DS ops).
// Steps: xor1 (quad_perm[1,0,3,2]=0xB1), xor2 (quad_perm[2,3,0,1]=0x4E),
// row_half_mirror (0x141, pairs quads), row_mirror (0x140, pairs 8-groups).
// All involutions; every lane of the 16-group ends with the identical sum.
__device__ __forceinline__ float red16(float x) {
    int t;
    t = __builtin_amdgcn_update_dpp(0, __float_as_int(x), 0xB1, 0xF, 0xF, true);
    x += __int_as_float(t);
    t = __builtin_amdgcn_update_dpp(0, __float_as_int(x), 0x4E, 0xF, 0xF, true);
    x += __int_as_float(t);
    t = __builtin_amdgcn_update_dpp(0, __float_as_int(x), 0x141, 0xF, 0xF, true);
    x += __int_as_float(t);
    t = __builtin_amdgcn_update_dpp(0, __float_as_int(x), 0x140, 0xF, 0xF, true);
    x += __int_as_float(t);
    return x;
}

__device__ __forceinline__ float dot8(float4 v0, float4 v1, float4 w0, float4 w1) {
    float d = v0.x * w0.x;
    d = fmaf(v0.y, w0.y, d); d = fmaf(v0.z, w0.z, d); d = fmaf(v0.w, w0.w, d);
    d = fmaf(v1.x, w1.x, d); d = fmaf(v1.y, w1.y, d); d = fmaf(v1.z, w1.z, d);
    d = fmaf(v1.w, w1.w, d);
    return d;
}

__device__ __forceinline__ float4 ld4(const float* p) {
    return *reinterpret_cast<const float4*>(p);
}

// Pass 1: per-chunk column sums of each graph -> sump[g][c][128]
__global__ __launch_bounds__(256) void k_sum(const float* __restrict__ x1,
                                             const float* __restrict__ x2,
                                             float* __restrict__ sump) {
    int g = blockIdx.x >> 7, c = blockIdx.x & (NCHUNK - 1);
    const float* xg = graph_ptr(x1, x2, g);
    int lane = threadIdx.x & 31, grp = threadIdx.x >> 5;
    int col = lane * 4;
    float ax = 0.f, ay = 0.f, az = 0.f, aw = 0.f;
    int r0 = c * CHROWS, r1 = min(r0 + CHROWS, NROWS);
    for (int r = r0 + grp; r < r1; r += 8) {
        float4 v = ld4(xg + (size_t)r * DIM + col);
        ax += v.x; ay += v.y; az += v.z; aw += v.w;
    }
    __shared__ float4 lds[256];
    lds[threadIdx.x] = make_float4(ax, ay, az, aw);
    __syncthreads();
    if (threadIdx.x < 32) {
        float4 t = lds[threadIdx.x];
        for (int k = 1; k < 8; ++k) {
            float4 o = lds[k * 32 + threadIdx.x];
            t.x += o.x; t.y += o.y; t.z += o.z; t.w += o.w;
        }
        *reinterpret_cast<float4*>(sump + ((size_t)g * NCHUNK + c) * DIM + threadIdx.x * 4) = t;
    }
}

// Glue: mean -> h = tanh(mean@W) -> wvec = Va + Wt@h, c = Vb.h + b
__global__ __launch_bounds__(128) void k_prep(const float* __restrict__ src, int phase,
                                              const float* __restrict__ W_att,
                                              const float* __restrict__ V_att,
                                              const float* __restrict__ Wt_att,
                                              const float* __restrict__ b_att,
                                              float* __restrict__ wv, float* __restrict__ cc) {
    int g = blockIdx.x >> 1, i = blockIdx.x & 1;
    int t = threadIdx.x;
    __shared__ float mean[DIM], h[DIM], red[DIM];
    float s = 0.f;
    if (phase == 1) {
        for (int c = 0; c < NCHUNK; ++c) s += src[((size_t)g * NCHUNK + c) * DIM + t];
    } else {
        for (int c = 0; c < NCHUNK; ++c) s += src[(((size_t)g * NCHUNK + c) * 2 + i) * DIM + t];
    }
    mean[t] = s / (float)NROWS;
    __syncthreads();
    const float* W = W_att + (size_t)i * DIM * DIM;
    float hv = 0.f;
    for (int d = 0; d < DIM; ++d) hv = fmaf(mean[d], W[d * DIM + t], hv);
    h[t] = tanhf(hv);
    __syncthreads();
    const float* Va = V_att + (size_t)i * 2 * DIM;
    const float* Vb = Va + DIM;
    const float* Wt = Wt_att + (size_t)i * DIM * DIM;
    float w = Va[t];
    for (int e = 0; e < DIM; ++e) w = fmaf(Wt[t * DIM + e], h[e], w);
    wv[((size_t)g * 2 + i) * DIM + t] = w;
    red[t] = Vb[t] * h[t];
    __syncthreads();
    for (int k = 64; k; k >>= 1) { if (t < k) red[t] += red[t + k]; __syncthreads(); }
    if (t == 0) cc[g * 2 + i] = red[0] + b_att[i];
}

// Pass 2: att1 per row (sign-select), accumulate out1 = sum att1*x (per-chunk partials)
// Layout: 16 lanes per row (8 floats each), 16 row-slots per 256-thread block.
__global__ __launch_bounds__(256) void k_pass2(const float* __restrict__ x1,
                                               const float* __restrict__ x2,
                                               const float* __restrict__ wv1,
                                               const float* __restrict__ c1,
                                               const float* __restrict__ U_att,
                                               float* __restrict__ o1p) {
    int g = blockIdx.x >> 7, c = blockIdx.x & (NCHUNK - 1);
    const float* xg = graph_ptr(x1, x2, g);
    int tid = threadIdx.x;
    int l16 = tid & 15, slot = tid >> 4;
    int colb = l16 * 8;
    float4 w0a = ld4(wv1 + ((size_t)g * 2 + 0) * DIM + colb);
    float4 w0b = ld4(wv1 + ((size_t)g * 2 + 0) * DIM + colb + 4);
    float4 w1a = ld4(wv1 + ((size_t)g * 2 + 1) * DIM + colb);
    float4 w1b = ld4(wv1 + ((size_t)g * 2 + 1) * DIM + colb + 4);
    float cc0 = c1[g * 2 + 0], cc1 = c1[g * 2 + 1];
    // att = u*sigmoid(clamp(s*1e12,-1,1)) == u*sigmoid(sign(s)) (|s|<1e-12 has prob ~0)
    float u0 = U_att[0], u1 = U_att[1];
    float sp = 1.f / (1.f + expf(-1.f)), sn = 1.f / (1.f + expf(1.f));
    float ap0 = u0 * sp, an0 = u0 * sn, ap1 = u1 * sp, an1 = u1 * sn;
    float4 a0l = make_float4(0, 0, 0, 0), a0h = make_float4(0, 0, 0, 0);
    float4 a1l = make_float4(0, 0, 0, 0), a1h = make_float4(0, 0, 0, 0);
    int r0 = c * CHROWS, r1 = min(r0 + CHROWS, NROWS);
    for (int r = r0 + slot; r < r1; r += 16) {
        const float* p = xg + (size_t)r * DIM + colb;
        float4 v0 = ld4(p), v1 = ld4(p + 4);
        float d0 = red16(dot8(v0, v1, w0a, w0b));
        float d1 = red16(dot8(v0, v1, w1a, w1b));
        float at0 = (d0 + cc0 >= 0.f) ? ap0 : an0;
        float at1 = (d1 + cc1 >= 0.f) ? ap1 : an1;
        a0l.x = fmaf(at0, v0.x, a0l.x); a0l.y = fmaf(at0, v0.y, a0l.y);
        a0l.z = fmaf(at0, v0.z, a0l.z); a0l.w = fmaf(at0, v0.w, a0l.w);
        a0h.x = fmaf(at0, v1.x, a0h.x); a0h.y = fmaf(at0, v1.y, a0h.y);
        a0h.z = fmaf(at0, v1.z, a0h.z); a0h.w = fmaf(at0, v1.w, a0h.w);
        a1l.x = fmaf(at1, v0.x, a1l.x); a1l.y = fmaf(at1, v0.y, a1l.y);
        a1l.z = fmaf(at1, v0.z, a1l.z); a1l.w = fmaf(at1, v0.w, a1l.w);
        a1h.x = fmaf(at1, v1.x, a1h.x); a1h.y = fmaf(at1, v1.y, a1h.y);
        a1h.z = fmaf(at1, v1.z, a1h.z); a1h.w = fmaf(at1, v1.w, a1h.w);
    }
    __shared__ float red[2][16][DIM];   // 16 KiB
    *reinterpret_cast<float4*>(&red[0][slot][colb]) = a0l;
    *reinterpret_cast<float4*>(&red[0][slot][colb + 4]) = a0h;
    *reinterpret_cast<float4*>(&red[1][slot][colb]) = a1l;
    *reinterpret_cast<float4*>(&red[1][slot][colb + 4]) = a1h;
    __syncthreads();
    int i = tid >> 7, d = tid & 127;
    float s = 0.f;
    #pragma unroll
    for (int k = 0; k < 16; ++k) s += red[i][k][d];
    o1p[(((size_t)g * NCHUNK + c) * 2 + i) * DIM + d] = s;
}

// Pass 3: recompute att1, att2 via sign-select, accumulate att1*att2*x
__global__ __launch_bounds__(256) void k_pass3(const float* __restrict__ x1,
                                               const float* __restrict__ x2,
                                               const float* __restrict__ wv1,
                                               const float* __restrict__ c1,
                                               const float* __restrict__ wv2,
                                               const float* __restrict__ c2,
                                               const float* __restrict__ U_att,
                                               float* __restrict__ o2p) {
    int g = blockIdx.x >> 7, c = blockIdx.x & (NCHUNK - 1);
    const float* xg = graph_ptr(x1, x2, g);
    int tid = threadIdx.x;
    int l16 = tid & 15, slot = tid >> 4;
    int colb = l16 * 8;
    float4 wA0a = ld4(wv1 + ((size_t)g * 2 + 0) * DIM + colb);
    float4 wA0b = ld4(wv1 + ((size_t)g * 2 + 0) * DIM + colb + 4);
    float4 wA1a = ld4(wv1 + ((size_t)g * 2 + 1) * DIM + colb);
    float4 wA1b = ld4(wv1 + ((size_t)g * 2 + 1) * DIM + colb + 4);
    float4 wB0a = ld4(wv2 + ((size_t)g * 2 + 0) * DIM + colb);
    float4 wB0b = ld4(wv2 + ((size_t)g * 2 + 0) * DIM + colb + 4);
    float4 wB1a = ld4(wv2 + ((size_t)g * 2 + 1) * DIM + colb);
    float4 wB1b = ld4(wv2 + ((size_t)g * 2 + 1) * DIM + colb + 4);
    float cA0 = c1[g * 2 + 0], cA1 = c1[g * 2 + 1];
    float cB0 = c2[g * 2 + 0], cB1 = c2[g * 2 + 1];
    float u0 = U_att[0], u1 = U_att[1];
    float sp = 1.f / (1.f + expf(-1.f)), sn = 1.f / (1.f + expf(1.f));
    float ap0 = u0 * sp, an0 = u0 * sn, ap1 = u1 * sp, an1 = u1 * sn;
    float4 a0l = make_float4(0, 0, 0, 0), a0h = make_float4(0, 0, 0, 0);
    float4 a1l = make_float4(0, 0, 0, 0), a1h = make_float4(0, 0, 0, 0);
    int r0 = c * CHROWS, r1 = min(r0 + CHROWS, NROWS);
    for (int r = r0 + slot; r < r1; r += 16) {
        const float* p = xg + (size_t)r * DIM + colb;
        float4 v0 = ld4(p), v1 = ld4(p + 4);
        float dA0 = red16(dot8(v0, v1, wA0a, wA0b));
        float dA1 = red16(dot8(v0, v1, wA1a, wA1b));
        float dB0 = red16(dot8(v0, v1, wB0a, wB0b));
        float dB1 = red16(dot8(v0, v1, wB1a, wB1b));
        float at10 = (dA0 + cA0 >= 0.f) ? ap0 : an0;
        float at11 = (dA1 + cA1 >= 0.f) ? ap1 : an1;
        float at20 = (fmaf(at10, dB0, cB0) >= 0.f) ? ap0 : an0;
        float at21 = (fmaf(at11, dB1, cB1) >= 0.f) ? ap1 : an1;
        float f0 = at10 * at20, f1 = at11 * at21;
        a0l.x = fmaf(f0, v0.x, a0l.x); a0l.y = fmaf(f0, v0.y, a0l.y);
        a0l.z = fmaf(f0, v0.z, a0l.z); a0l.w = fmaf(f0, v0.w, a0l.w);
        a0h.x = fmaf(f0, v1.x, a0h.x); a0h.y = fmaf(f0, v1.y, a0h.y);
        a0h.z = fmaf(f0, v1.z, a0h.z); a0h.w = fmaf(f0, v1.w, a0h.w);
        a1l.x = fmaf(f1, v0.x, a1l.x); a1l.y = fmaf(f1, v0.y, a1l.y);
        a1l.z = fmaf(f1, v0.z, a1l.z); a1l.w = fmaf(f1, v0.w, a1l.w);
        a1h.x = fmaf(f1, v1.x, a1h.x); a1h.y = fmaf(f1, v1.y, a1h.y);
        a1h.z = fmaf(f1, v1.z, a1h.z); a1h.w = fmaf(f1, v1.w, a1h.w);
    }
    __shared__ float red[2][16][DIM];   // 16 KiB
    *reinterpret_cast<float4*>(&red[0][slot][colb]) = a0l;
    *reinterpret_cast<float4*>(&red[0][slot][colb + 4]) = a0h;
    *reinterpret_cast<float4*>(&red[1][slot][colb]) = a1l;
    *reinterpret_cast<float4*>(&red[1][slot][colb + 4]) = a1h;
    __syncthreads();
    int i = tid >> 7, d = tid & 127;
    float s = 0.f;
    #pragma unroll
    for (int k = 0; k < 16; ++k) s += red[i][k][d];
    o2p[(((size_t)g * NCHUNK + c) * 2 + i) * DIM + d] = s;
}

// Reduce per-chunk out2 partials -> g vectors [16][256] (concat i=0, i=1)
__global__ __launch_bounds__(256) void k_reduceG(const float* __restrict__ o2p,
                                                 float* __restrict__ gv) {
    int g = blockIdx.x, t = threadIdx.x;
    int i = t >> 7, d = t & 127;
    float s = 0.f;
    for (int c = 0; c < NCHUNK; ++c) s += o2p[(((size_t)g * NCHUNK + c) * 2 + i) * DIM + d];
    gv[(size_t)g * 256 + t] = s;
}

// NTN raw scores: one block per (pair b, feature f)
__global__ __launch_bounds__(256) void k_ntn(const float* __restrict__ gv,
                                             const float* __restrict__ V_ntn,
                                             const float* __restrict__ W_ntn,
                                             const float* __restrict__ b_ntn,
                                             float* __restrict__ sout) {
    int b = blockIdx.x >> 4, f = blockIdx.x & 15;
    int e = threadIdx.x;
    __shared__ float g1s[256], g2s[256], red[256];
    g1s[e] = gv[(size_t)b * 256 + e];
    g2s[e] = gv[(size_t)(8 + b) * 256 + e];
    __syncthreads();
    const float* Wf = W_ntn + (size_t)f * 256 * 256;
    float acc = 0.f;
    for (int d = 0; d < 256; ++d) acc = fmaf(Wf[(size_t)d * 256 + e], g1s[d], acc);
    float p = acc * g2s[e];
    p = fmaf(V_ntn[(size_t)f * 512 + e], g1s[e], p);
    p = fmaf(V_ntn[(size_t)f * 512 + 256 + e], g2s[e], p);
    red[e] = p;
    __syncthreads();
    for (int k = 128; k; k >>= 1) { if (e < k) red[e] += red[e + k]; __syncthreads(); }
    if (e == 0) sout[b * 16 + f] = red[0] + b_ntn[f];
}

// Final: l1-normalize, relu, projection chain -> out[b]
__global__ __launch_bounds__(64) void k_out(const float* __restrict__ sout,
                                            const float* __restrict__ p0,
                                            const float* __restrict__ p1,
                                            const float* __restrict__ p2,
                                            const float* __restrict__ p3,
                                            float* __restrict__ out) {
    int b = blockIdx.x;
    if (threadIdx.x != 0) return;
    float s[16]; float l1 = 0.f;
    for (int f = 0; f < 16; ++f) { s[f] = sout[b * 16 + f]; l1 += fabsf(s[f]); }
    float inv = 1.f / fmaxf(l1, EPSV);
    float y[16];
    for (int f = 0; f < 16; ++f) { float t = s[f] * inv; y[f] = t > 0.f ? t : 0.f; }
    float v2[4], v1[8], P[16];
    for (int j = 0; j < 4; ++j) v2[j] = p3[0] * p2[j] + p3[1] * p2[4 + j];
    for (int j = 0; j < 8; ++j) { float a = 0.f; for (int k = 0; k < 4; ++k) a = fmaf(v2[k], p1[k * 8 + j], a); v1[j] = a; }
    for (int j = 0; j < 16; ++j) { float a = 0.f; for (int k = 0; k < 8; ++k) a = fmaf(v1[k], p0[k * 16 + j], a); P[j] = a; }
    float o = 0.f;
    for (int f = 0; f < 16; ++f) o = fmaf(P[f], y[f], o);
    out[b] = o;
}

extern "C" void kernel_launch(void* const* d_in, const int* in_sizes, int n_in,
                              void* d_out, int out_size, void* d_ws, size_t ws_size,
                              hipStream_t stream) {
    const float* x1    = (const float*)d_in[0];
    const float* x2    = (const float*)d_in[1];
    const float* W_att = (const float*)d_in[2];
    const float* V_att = (const float*)d_in[3];
    const float* Wt_att= (const float*)d_in[4];
    const float* U_att = (const float*)d_in[5];
    const float* b_att = (const float*)d_in[6];
    const float* V_ntn = (const float*)d_in[7];
    const float* W_ntn = (const float*)d_in[8];
    const float* b_ntn = (const float*)d_in[9];
    const float* p0    = (const float*)d_in[10];
    const float* p1    = (const float*)d_in[11];
    const float* p2    = (const float*)d_in[12];
    const float* p3    = (const float*)d_in[13];
    float* ws  = (float*)d_ws;
    float* out = (float*)d_out;

    k_sum<<<NGRAPH * NCHUNK, 256, 0, stream>>>(x1, x2, ws + OFF_SUMP);
    k_prep<<<NGRAPH * 2, 128, 0, stream>>>(ws + OFF_SUMP, 1, W_att, V_att, Wt_att, b_att,
                                           ws + OFF_WV1, ws + OFF_C1);
    k_pass2<<<NGRAPH * NCHUNK, 256, 0, stream>>>(x1, x2, ws + OFF_WV1, ws + OFF_C1, U_att,
                                                 ws + OFF_O1P);
    k_prep<<<NGRAPH * 2, 128, 0, stream>>>(ws + OFF_O1P, 2, W_att, V_att, Wt_att, b_att,
                                           ws + OFF_WV2, ws + OFF_C2);
    k_pass3<<<NGRAPH * NCHUNK, 256, 0, stream>>>(x1, x2, ws + OFF_WV1, ws + OFF_C1,
                                                 ws + OFF_WV2, ws + OFF_C2, U_att,
                                                 ws + OFF_O2P);
    k_reduceG<<<NGRAPH, 256, 0, stream>>>(ws + OFF_O2P, ws + OFF_G);
    k_ntn<<<8 * 16, 256, 0, stream>>>(ws + OFF_G, V_ntn, W_ntn, b_ntn, ws + OFF_S);
    k_out<<<8, 64, 0, stream>>>(ws + OFF_S, p0, p1, p2, p3, out);
}